// Round 8
// baseline (90.836 us; speedup 1.0000x reference)
//
#include <hip/hip_runtime.h>

// left/right: [B=4, C=32, H=64, W=128] fp32 ; out: [B, 2C=64, D=48, H, W] fp32
#define BB 4
#define CC 32
#define HH 64
#define WW 128
#define DD 48
#define PLANE (HH * WW)        // 8192 floats = 32 KB
#define G_F4 (DD * HH * WW/4)  // 98304 float4 per (b,c2) group

typedef float f32x4 __attribute__((ext_vector_type(4)));

// Round-0 flat linear sweep (the proven 6.2+ TB/s store order on this chip)
// + bijective XCD-contiguous swizzle: 98304 blocks, block i -> XCD i%8
// (hardware round-robin), remapped so XCD k linearly sweeps flat float4
// range [k*12288*256, (k+1)*12288*256). Consequence: each 32 KB input plane
// is touched by exactly ONE XCD, whose concurrent blocks share it via L1/L2
// -> HBM reads ~8 MB (vs round 0's 384 MB), while the store stream per XCD
// is a single ascending fill-like sweep. NT stores (write-once, skip L2
// allocate); input reads cached normally.
__global__ __launch_bounds__(256) void cost_vol_kernel(
    const float* __restrict__ left,
    const float* __restrict__ right,
    float* __restrict__ out)
{
    const int i   = blockIdx.x;
    const int xcd = i & 7;
    const int j   = i >> 3;                   // 0..12287
    const int fb  = xcd * 12288 + j;          // flat block in output order
    const int f   = (fb << 8) + threadIdx.x;  // flat float4 index, < 25,165,824

    const int g = f / G_F4;                   // magic-mul (const 98304)
    const int r = f - g * G_F4;
    const int d = r >> 11;                    // 2048 float4 per plane
    const int p = r & 2047;                   // float4 within plane
    const int w0 = (p & 31) << 2;

    const int b  = g >> 6;
    const int c2 = g & 63;

    f32x4 v;
    if (c2 < CC) {
        // left: aligned float4 copy + mask (block-uniform branch)
        const float* plane = left + (size_t)(b * CC + c2) * PLANE;
        const f32x4 lv = *reinterpret_cast<const f32x4*>(plane + (p << 2));
        v.x = (w0     >= d) ? lv.x : 0.0f;
        v.y = (w0 + 1 >= d) ? lv.y : 0.0f;
        v.z = (w0 + 2 >= d) ? lv.z : 0.0f;
        v.w = (w0 + 3 >= d) ? lv.w : 0.0f;
    } else {
        // right: 4 scalar gathers at w-d (L1/L2-hit; plane is XCD-resident)
        const float* row = right + (size_t)(b * CC + (c2 - CC)) * PLANE
                         + ((p >> 5) << 7);   // + h*128
        const int e  = w0 - d;
        const int x0 = e     < 0 ? 0 : e;
        const int x1 = e + 1 < 0 ? 0 : e + 1;
        const int x2 = e + 2 < 0 ? 0 : e + 2;
        const int x3 = e + 3 < 0 ? 0 : e + 3;
        const float r0 = row[x0];
        const float r1 = row[x1];
        const float r2 = row[x2];
        const float r3 = row[x3];
        v.x = (e     >= 0) ? r0 : 0.0f;
        v.y = (e + 1 >= 0) ? r1 : 0.0f;
        v.z = (e + 2 >= 0) ? r2 : 0.0f;
        v.w = (e + 3 >= 0) ? r3 : 0.0f;
    }

    __builtin_nontemporal_store(v, reinterpret_cast<f32x4*>(out + (size_t)f * 4));
}

extern "C" void kernel_launch(void* const* d_in, const int* in_sizes, int n_in,
                              void* d_out, int out_size, void* d_ws, size_t ws_size,
                              hipStream_t stream) {
    const float* left  = (const float*)d_in[0];
    const float* right = (const float*)d_in[1];
    float* out = (float*)d_out;

    const int total4 = BB * 2 * CC * DD * HH * (WW / 4);  // 25,165,824
    const int block  = 256;
    const int grid   = total4 / block;                    // 98,304 (%8 == 0)
    cost_vol_kernel<<<grid, block, 0, stream>>>(left, right, out);
}

// Round 9
// 76.876 us; speedup vs baseline: 1.1816x; 1.1816x over previous
//
#include <hip/hip_runtime.h>

// left/right: [B=4, C=32, H=64, W=128] fp32 ; out: [B, 2C=64, D=48, H, W] fp32
#define BB 4
#define CC 32
#define HH 64
#define WW 128
#define DD 48
#define PLANE (HH * WW)          // 8192 floats = 32 KB
#define G_F4 (DD * HH * WW / 4)  // 98304 float4 per (b,c2) group

#define NBLK 2048
#define NTHR 256
#define SPAN (NBLK * NTHR)       // 524288 float4 = 8 MB front
#define NIT  48                  // 25,165,824 / SPAN

typedef float f32x4 __attribute__((ext_vector_type(4)));

// fill-shaped writer with big blocks: 2048 blocks x 256 thr grid-stride the
// flat output. At any instant the chip's stores form ONE dense 8 MB front
// sweeping linearly (fillBuffer's 6.9 TB/s shape), while each thread issues
// a 48-deep store chain (dodges the ~1080 blocks/us CP dispatch cap that
// sank R8). Per iter a block's 4 KB chunk is inside one plane -> (g,d)
// block-uniform branch. Read working set ~6 input planes chip-wide; the
// die-level 256 MB L3 serves cross-XCD re-reads, HBM fetch stays ~8 MB.
__global__ __launch_bounds__(NTHR) void cost_vol_kernel(
    const float* __restrict__ left,
    const float* __restrict__ right,
    float* __restrict__ out)
{
    int f = blockIdx.x * NTHR + threadIdx.x;   // flat float4 index

    #pragma unroll 4
    for (int it = 0; it < NIT; ++it, f += SPAN) {
        const int g  = f / G_F4;               // magic-mul (const)
        const int r  = f - g * G_F4;
        const int d  = r >> 11;                // 2048 float4 per plane
        const int p  = r & 2047;               // float4 within plane
        const int w0 = (p & 31) << 2;
        const int b  = g >> 6;
        const int c2 = g & 63;

        f32x4 v;
        if (c2 < CC) {
            // left: aligned coalesced float4 + mask (block-uniform branch)
            const float* plane = left + (size_t)(b * CC + c2) * PLANE;
            const f32x4 lv = *reinterpret_cast<const f32x4*>(plane + (p << 2));
            v.x = (w0     >= d) ? lv.x : 0.0f;
            v.y = (w0 + 1 >= d) ? lv.y : 0.0f;
            v.z = (w0 + 2 >= d) ? lv.z : 0.0f;
            v.w = (w0 + 3 >= d) ? lv.w : 0.0f;
        } else {
            // right: 4 scalar gathers at w-d (L1/L3-resident plane)
            const float* row = right + (size_t)(b * CC + (c2 - CC)) * PLANE
                             + ((p >> 5) << 7);        // + h*128
            const int e  = w0 - d;
            const int x0 = e     < 0 ? 0 : e;
            const int x1 = e + 1 < 0 ? 0 : e + 1;
            const int x2 = e + 2 < 0 ? 0 : e + 2;
            const int x3 = e + 3 < 0 ? 0 : e + 3;
            const float r0 = row[x0];
            const float r1 = row[x1];
            const float r2 = row[x2];
            const float r3 = row[x3];
            v.x = (e     >= 0) ? r0 : 0.0f;
            v.y = (e + 1 >= 0) ? r1 : 0.0f;
            v.z = (e + 2 >= 0) ? r2 : 0.0f;
            v.w = (e + 3 >= 0) ? r3 : 0.0f;
        }

        __builtin_nontemporal_store(v, reinterpret_cast<f32x4*>(out + (size_t)f * 4));
    }
}

extern "C" void kernel_launch(void* const* d_in, const int* in_sizes, int n_in,
                              void* d_out, int out_size, void* d_ws, size_t ws_size,
                              hipStream_t stream) {
    const float* left  = (const float*)d_in[0];
    const float* right = (const float*)d_in[1];
    float* out = (float*)d_out;

    cost_vol_kernel<<<NBLK, NTHR, 0, stream>>>(left, right, out);
}

// Round 10
// 71.070 us; speedup vs baseline: 1.2781x; 1.0817x over previous
//
#include <hip/hip_runtime.h>

// left/right: [B=4, C=32, H=64, W=128] fp32 ; out: [B, 2C=64, D=48, H, W] fp32
#define BB 4
#define CC 32
#define HH 64
#define WW 128
#define DD 48
#define HT 16                 // h-rows per block
#define RSTRIDE 160           // swizzled LDS row stride

typedef float f32x4 __attribute__((ext_vector_type(4)));

// FINAL (= round-7 kernel, the measured optimum of the store-shape matrix):
// 1024 blocks x 512 threads (8192 waves = whole chip resident in one shot).
// Block = (half, b, c, hq): ONE output stream per block — left blocks keep
// their float4 in registers (no LDS at all); right blocks stage their 16
// input rows in LDS once (swizzled slot=i+(i>>2): gather stride 5, all 32
// banks) and gather per d. All stores nontemporal (write-once stream, skip
// L2 allocate). Per d the block stores 8 KB contiguous, hopping 32 KB per
// d-step; tested alternatives (full-plane sweeps, 192 KB contiguous spans,
// XCD-contiguous flat sweep, dense-front grid-stride) were all slower.
__global__ __launch_bounds__(512) void cost_vol_kernel(
    const float* __restrict__ left,
    const float* __restrict__ right,
    float* __restrict__ out)
{
    __shared__ float lds_r[HT][RSTRIDE];   // 10 KB, right blocks only

    const int bx   = blockIdx.x;
    const int half = bx & 1;               // alternate halves across XCD rr
    const int idx  = bx >> 1;              // 0..511
    const int hq   = idx & 3;              // H/HT = 4
    const int c    = (idx >> 2) & 31;      // C = 32
    const int b    = idx >> 7;             // B = 4
    const int h0   = hq * HT;

    const int t     = threadIdx.x;
    const int w4    = t & 31;
    const int h_loc = t >> 5;              // 0..15
    const int w0    = w4 << 2;

    const int bc = b * CC + c;

    // out[b][c2][d][h][w], c2 = half*32 + c
    float* op = out +
        ((((size_t)(b * 2 * CC + half * CC + c) * DD) * HH) + h0 + h_loc) * WW + w0;

    if (half == 0) {
        // ---- LEFT: registers only, mask per d, one NT store per iter -------
        const float* lrow = left + ((bc * HH) + h0 + h_loc) * WW;
        const f32x4 lv = *reinterpret_cast<const f32x4*>(lrow + w0);

        #pragma unroll 8
        for (int d = 0; d < DD; ++d) {
            f32x4 v;
            v.x = (w0     >= d) ? lv.x : 0.0f;
            v.y = (w0 + 1 >= d) ? lv.y : 0.0f;
            v.z = (w0 + 2 >= d) ? lv.z : 0.0f;
            v.w = (w0 + 3 >= d) ? lv.w : 0.0f;
            __builtin_nontemporal_store(v, reinterpret_cast<f32x4*>(op));
            op += HH * WW;
        }
    } else {
        // ---- RIGHT: stage 16 rows once, gather per d, one NT store per iter
        {
            const int row = t >> 5;        // 0..15
            const int i0  = (t & 31) << 2;
            const float* rrow = right + ((bc * HH) + h0 + row) * WW;
            const f32x4 rv = *reinterpret_cast<const f32x4*>(rrow + i0);
            lds_r[row][(i0    ) + ((i0    ) >> 2)] = rv.x;
            lds_r[row][(i0 + 1) + ((i0 + 1) >> 2)] = rv.y;
            lds_r[row][(i0 + 2) + ((i0 + 2) >> 2)] = rv.z;
            lds_r[row][(i0 + 3) + ((i0 + 3) >> 2)] = rv.w;
        }
        __syncthreads();                   // block-uniform branch: safe

        const float* rl = lds_r[h_loc];

        #pragma unroll 6
        for (int d = 0; d < DD; ++d) {
            const int e  = w0 - d;
            const int i0 = e,     i1 = e + 1, i2 = e + 2, i3 = e + 3;
            const int x0 = i0 < 0 ? 0 : i0, x1 = i1 < 0 ? 0 : i1;
            const int x2 = i2 < 0 ? 0 : i2, x3 = i3 < 0 ? 0 : i3;
            const float r0 = rl[x0 + (x0 >> 2)];
            const float r1 = rl[x1 + (x1 >> 2)];
            const float r2 = rl[x2 + (x2 >> 2)];
            const float r3 = rl[x3 + (x3 >> 2)];
            f32x4 v;
            v.x = (i0 >= 0) ? r0 : 0.0f;
            v.y = (i1 >= 0) ? r1 : 0.0f;
            v.z = (i2 >= 0) ? r2 : 0.0f;
            v.w = (i3 >= 0) ? r3 : 0.0f;
            __builtin_nontemporal_store(v, reinterpret_cast<f32x4*>(op));
            op += HH * WW;
        }
    }
}

extern "C" void kernel_launch(void* const* d_in, const int* in_sizes, int n_in,
                              void* d_out, int out_size, void* d_ws, size_t ws_size,
                              hipStream_t stream) {
    const float* left  = (const float*)d_in[0];
    const float* right = (const float*)d_in[1];
    float* out = (float*)d_out;

    const int grid  = 2 * BB * CC * (HH / HT);   // 1024
    const int block = 512;
    cost_vol_kernel<<<grid, block, 0, stream>>>(left, right, out);
}